// Round 4
// baseline (326.160 us; speedup 1.0000x reference)
//
#include <hip/hip_runtime.h>

#define HIDDEN 16
#define CB 1024         // nodes per coarse bucket (power of two)
#define CB_SHIFT 10
#define NCB_MAX 512     // max coarse buckets (n <= 512K; also src<<10 needs n < 4M)
#define CHUNK 8192      // edges per block in hist/fill passes

// ======================= coarse-binned path =======================

__global__ void k_zero_cnt(unsigned int* cnt, int nb) {
    int i = blockIdx.x * blockDim.x + threadIdx.x;
    if (i < nb) cnt[i] = 0u;
}

__global__ void k_hist_c(const int* __restrict__ dst, int e, int ncb,
                         unsigned int* __restrict__ cntc) {
    __shared__ unsigned int h[NCB_MAX];
    for (int i = threadIdx.x; i < ncb; i += blockDim.x) h[i] = 0u;
    __syncthreads();
    int start = blockIdx.x * CHUNK;
    int end = min(start + CHUNK, e);
    for (int i = start + threadIdx.x; i < end; i += blockDim.x)
        atomicAdd(&h[((unsigned)dst[i]) >> CB_SHIFT], 1u);
    __syncthreads();
    for (int i = threadIdx.x; i < ncb; i += blockDim.x)
        if (h[i]) atomicAdd(&cntc[i], h[i]);
}

// single-block exclusive scan of cntc -> base, cursor
__global__ void k_scan(const unsigned int* __restrict__ cnt, int nb,
                       unsigned int* __restrict__ base,
                       unsigned int* __restrict__ cursor) {
    __shared__ unsigned int tsum[256];
    int t = threadIdx.x;
    int K = (nb + 255) / 256;
    unsigned int s = 0;
    for (int k = 0; k < K; k++) {
        int i = t * K + k;
        if (i < nb) s += cnt[i];
    }
    tsum[t] = s;
    __syncthreads();
    for (int off = 1; off < 256; off <<= 1) {
        unsigned int v = 0;
        if (t >= off) v = tsum[t - off];
        __syncthreads();
        if (t >= off) tsum[t] += v;
        __syncthreads();
    }
    unsigned int run = (t == 0) ? 0u : tsum[t - 1];
    for (int k = 0; k < K; k++) {
        int i = t * K + k;
        if (i < nb) { base[i] = run; cursor[i] = run; run += cnt[i]; }
    }
}

// partition edges into 98 coarse buckets; runs of ~84 consecutive records per
// bucket per chunk -> write amplification ~1.2x (vs 7x with 1563 fine buckets)
__global__ void k_fill_c(const int* __restrict__ src, const int* __restrict__ dst,
                         int e, int ncb, unsigned int* cursorc,
                         unsigned int* __restrict__ tmp) {
    __shared__ unsigned int h[NCB_MAX];
    __shared__ unsigned int lbase[NCB_MAX];
    for (int i = threadIdx.x; i < ncb; i += blockDim.x) h[i] = 0u;
    __syncthreads();
    int start = blockIdx.x * CHUNK;
    int end = min(start + CHUNK, e);
    for (int i = start + threadIdx.x; i < end; i += blockDim.x)
        atomicAdd(&h[((unsigned)dst[i]) >> CB_SHIFT], 1u);
    __syncthreads();
    for (int i = threadIdx.x; i < ncb; i += blockDim.x) {
        unsigned int c = h[i];
        lbase[i] = c ? atomicAdd(&cursorc[i], c) : 0u;
        h[i] = 0u;  // reuse as local rank cursor
    }
    __syncthreads();
    for (int i = start + threadIdx.x; i < end; i += blockDim.x) {
        unsigned int d = (unsigned)dst[i];
        unsigned int b = d >> CB_SHIFT;
        unsigned int r = atomicAdd(&h[b], 1u);
        tmp[lbase[b] + r] = (((unsigned)src[i]) << CB_SHIFT) | (d & (CB - 1u));
    }
}

// one 1024-thread block per coarse bucket: LDS degree histogram -> inv
__global__ __launch_bounds__(CB) void
k_deg_inv(const unsigned int* __restrict__ tmp,
          const unsigned int* __restrict__ basec,
          const unsigned int* __restrict__ cntc,
          int n, float* __restrict__ inv) {
    __shared__ unsigned int degl[CB];
    int t = threadIdx.x;
    degl[t] = 1u;  // self-loop
    __syncthreads();
    unsigned int s = basec[blockIdx.x], m = cntc[blockIdx.x];
    for (unsigned int i = t; i < m; i += CB)
        atomicAdd(&degl[tmp[s + i] & (CB - 1u)], 1u);
    __syncthreads();
    int node = blockIdx.x * CB + t;
    if (node < n) inv[node] = rsqrtf((float)degl[t]);
}

// layer-1 aggregate of raw x (linearity: segsum(norm*x[src]) @ W1) with fused
// epilogue: self-loop + W1 + b1 + relu + W2 -> t2, and out init (b2 + self).
__global__ __launch_bounds__(CB) void
k_s1(const unsigned int* __restrict__ tmp,
     const unsigned int* __restrict__ basec,
     const unsigned int* __restrict__ cntc,
     const float* __restrict__ inv, const float* __restrict__ x,
     const float* __restrict__ W1, const float* __restrict__ b1,
     const float* __restrict__ W2, const float* __restrict__ b2,
     float* __restrict__ t2, float* __restrict__ out, int n) {
    __shared__ float a0[CB], a1[CB], a2[CB], invl[CB];  // 16 KB
    int t = threadIdx.x;
    int node = blockIdx.x * CB + t;
    a0[t] = 0.f; a1[t] = 0.f; a2[t] = 0.f;
    invl[t] = (node < n) ? inv[node] : 0.f;
    __syncthreads();
    unsigned int s = basec[blockIdx.x], m = cntc[blockIdx.x];
    for (unsigned int i = t; i < m; i += CB) {
        unsigned int rec = tmp[s + i];            // coalesced
        unsigned int srcn = rec >> CB_SHIFT;
        unsigned int dl = rec & (CB - 1u);
        float nm = inv[srcn] * invl[dl];          // inv: 400 KB, L2-hit
        float x0 = x[srcn * 3];                   // x: 1.2 MB, L2-hit
        float x1 = x[srcn * 3 + 1];
        float x2 = x[srcn * 3 + 2];
        atomicAdd(&a0[dl], nm * x0);
        atomicAdd(&a1[dl], nm * x1);
        atomicAdd(&a2[dl], nm * x2);
    }
    __syncthreads();
    if (node < n) {
        float iv = invl[t];
        float selfc = iv * iv;                    // self-loop norm = 1/deg
        float v0 = a0[t] + x[node * 3] * selfc;
        float v1 = a1[t] + x[node * 3 + 1] * selfc;
        float v2 = a2[t] + x[node * 3 + 2] * selfc;
        float acc = 0.f;
#pragma unroll
        for (int j = 0; j < HIDDEN; j++) {
            float h = fmaxf(fmaf(v0, W1[j], fmaf(v1, W1[HIDDEN + j],
                           fmaf(v2, W1[2 * HIDDEN + j], b1[j]))), 0.f);
            acc += h * W2[j];
        }
        t2[node] = acc;
        out[node] = b2[0] + acc * selfc;          // out init (bucket-exclusive)
    }
}

// layer-2 aggregate: LDS accumulate + plain += into out (bucket-exclusive,
// k_s1 already wrote the init; no atomics on global needed)
__global__ __launch_bounds__(CB) void
k_s2(const unsigned int* __restrict__ tmp,
     const unsigned int* __restrict__ basec,
     const unsigned int* __restrict__ cntc,
     const float* __restrict__ inv, const float* __restrict__ t2,
     float* __restrict__ out, int n) {
    __shared__ float o[CB], invl[CB];
    int t = threadIdx.x;
    int node = blockIdx.x * CB + t;
    o[t] = 0.f;
    invl[t] = (node < n) ? inv[node] : 0.f;
    __syncthreads();
    unsigned int s = basec[blockIdx.x], m = cntc[blockIdx.x];
    for (unsigned int i = t; i < m; i += CB) {
        unsigned int rec = tmp[s + i];
        unsigned int srcn = rec >> CB_SHIFT;
        unsigned int dl = rec & (CB - 1u);
        atomicAdd(&o[dl], inv[srcn] * invl[dl] * t2[srcn]);  // t2: 400 KB, L2-hit
    }
    __syncthreads();
    if (node < n) out[node] += o[t];
}

// ======================= fallback (global-atomic) path =======================

__global__ void k_init_deg(unsigned int* deg, int n) {
    int i = blockIdx.x * blockDim.x + threadIdx.x;
    if (i < n) deg[i] = 1u;
}
__global__ void k_count_deg(const int* __restrict__ dst, unsigned int* deg, int e) {
    int i = blockIdx.x * blockDim.x + threadIdx.x;
    if (i < e) atomicAdd(&deg[dst[i]], 1u);
}
__global__ void k_inv(const unsigned int* __restrict__ deg, float* __restrict__ inv, int n) {
    int i = blockIdx.x * blockDim.x + threadIdx.x;
    if (i < n) inv[i] = rsqrtf((float)deg[i]);
}
__global__ void k_transform1(const float* __restrict__ x, const float* __restrict__ W1,
                             const float* __restrict__ b1, const float* __restrict__ inv,
                             float* __restrict__ t1, float* __restrict__ acc1, int n) {
    int tid = blockIdx.x * blockDim.x + threadIdx.x;
    if (tid >= n * HIDDEN) return;
    int i = tid >> 4, j = tid & 15;
    float t = x[3 * i] * W1[j] + x[3 * i + 1] * W1[HIDDEN + j] + x[3 * i + 2] * W1[2 * HIDDEN + j];
    t1[tid] = t;
    float iv = inv[i];
    acc1[tid] = b1[j] + t * iv * iv;
}
__global__ void k_scatter1(const int* __restrict__ src, const int* __restrict__ dst,
                           const float* __restrict__ inv, const float* __restrict__ t1,
                           float* acc1, int e) {
    long long tid = (long long)blockIdx.x * blockDim.x + threadIdx.x;
    if (tid >= (long long)e * HIDDEN) return;
    int eid = (int)(tid >> 4), j = (int)(tid & 15);
    int s = src[eid], d = dst[eid];
    atomicAdd(&acc1[d * HIDDEN + j], inv[s] * inv[d] * t1[s * HIDDEN + j]);
}
__global__ void k_transform2(const float* __restrict__ acc1, const float* __restrict__ W2,
                             const float* __restrict__ b2, const float* __restrict__ inv,
                             float* __restrict__ t2, float* __restrict__ out, int n) {
    int i = blockIdx.x * blockDim.x + threadIdx.x;
    if (i >= n) return;
    float t = 0.f;
#pragma unroll
    for (int j = 0; j < HIDDEN; j++) t += fmaxf(acc1[i * HIDDEN + j], 0.f) * W2[j];
    t2[i] = t;
    float iv = inv[i];
    out[i] = b2[0] + t * iv * iv;
}
__global__ void k_scatter2(const int* __restrict__ src, const int* __restrict__ dst,
                           const float* __restrict__ inv, const float* __restrict__ t2,
                           float* out, int e) {
    int i = blockIdx.x * blockDim.x + threadIdx.x;
    if (i >= e) return;
    int s = src[i], d = dst[i];
    atomicAdd(&out[d], inv[s] * inv[d] * t2[s]);
}

// ======================= launch =======================

extern "C" void kernel_launch(void* const* d_in, const int* in_sizes, int n_in,
                              void* d_out, int out_size, void* d_ws, size_t ws_size,
                              hipStream_t stream) {
    const float* x  = (const float*)d_in[0];
    const int*   ei = (const int*)d_in[1];
    const float* W1 = (const float*)d_in[2];
    const float* b1 = (const float*)d_in[3];
    const float* W2 = (const float*)d_in[4];
    const float* b2 = (const float*)d_in[5];
    float* out = (float*)d_out;

    int n = in_sizes[0] / 3;
    int e = in_sizes[1] / 2;
    const int* src = ei;
    const int* dst = ei + e;
    const int B = 256;

    int ncb = (n + CB - 1) / CB;
    size_t need = (size_t)ncb * 4 * 3 + (size_t)e * 4 + (size_t)n * 8;
    bool use_binned = (ncb <= NCB_MAX) && (ws_size >= need);

    if (use_binned) {
        unsigned int* cntc    = (unsigned int*)d_ws;          // ncb
        unsigned int* basec   = cntc + ncb;                   // ncb
        unsigned int* cursorc = basec + ncb;                  // ncb
        unsigned int* tmp     = cursorc + ncb;                // e
        float* inv = (float*)(tmp + e);                       // n
        float* t2  = inv + n;                                 // n

        int gridE = (e + CHUNK - 1) / CHUNK;
        k_zero_cnt<<<(ncb + B - 1) / B, B, 0, stream>>>(cntc, ncb);
        k_hist_c<<<gridE, B, 0, stream>>>(dst, e, ncb, cntc);
        k_scan<<<1, B, 0, stream>>>(cntc, ncb, basec, cursorc);
        k_fill_c<<<gridE, B, 0, stream>>>(src, dst, e, ncb, cursorc, tmp);
        k_deg_inv<<<ncb, CB, 0, stream>>>(tmp, basec, cntc, n, inv);
        k_s1<<<ncb, CB, 0, stream>>>(tmp, basec, cntc, inv, x, W1, b1, W2, b2, t2, out, n);
        k_s2<<<ncb, CB, 0, stream>>>(tmp, basec, cntc, inv, t2, out, n);
    } else {
        unsigned int* deg = (unsigned int*)d_ws;
        float* inv  = (float*)(deg + n);
        float* t1   = inv + n;
        float* acc1 = t1 + (size_t)n * HIDDEN;
        float* t2   = acc1 + (size_t)n * HIDDEN;

        k_init_deg<<<(n + B - 1) / B, B, 0, stream>>>(deg, n);
        k_count_deg<<<(e + B - 1) / B, B, 0, stream>>>(dst, deg, e);
        k_inv<<<(n + B - 1) / B, B, 0, stream>>>(deg, inv, n);
        k_transform1<<<((long long)n * HIDDEN + B - 1) / B, B, 0, stream>>>(x, W1, b1, inv, t1, acc1, n);
        k_scatter1<<<((long long)e * HIDDEN + B - 1) / B, B, 0, stream>>>(src, dst, inv, t1, acc1, e);
        k_transform2<<<(n + B - 1) / B, B, 0, stream>>>(acc1, W2, b2, inv, t2, out, n);
        k_scatter2<<<(e + B - 1) / B, B, 0, stream>>>(src, dst, inv, t2, out, e);
    }
}

// Round 5
// 232.542 us; speedup vs baseline: 1.4026x; 1.4026x over previous
//
#include <hip/hip_runtime.h>

#define HIDDEN 16
#define CB 1024         // nodes per coarse bucket (power of two)
#define CB_SHIFT 10
#define NCB_MAX 512     // max coarse buckets
#define CHUNK 8192      // edges per block in hist/fill passes
#define SPL 16          // slice-blocks per bucket in accumulate kernels

// ======================= coarse-binned split path =======================

// zero agg0..agg2+deg (4n contiguous words) and cntc (ncb words)
__global__ void k_zero(unsigned int* aggdeg, int n4, unsigned int* cntc, int ncb) {
    int i = blockIdx.x * blockDim.x + threadIdx.x;
    if (i < n4) aggdeg[i] = 0u;
    else if (i < n4 + ncb) cntc[i - n4] = 0u;
}

__global__ void k_hist_c(const int* __restrict__ dst, int e, int ncb,
                         unsigned int* __restrict__ cntc) {
    __shared__ unsigned int h[NCB_MAX];
    for (int i = threadIdx.x; i < ncb; i += blockDim.x) h[i] = 0u;
    __syncthreads();
    int start = blockIdx.x * CHUNK;
    int end = min(start + CHUNK, e);
    for (int i = start + threadIdx.x; i < end; i += blockDim.x)
        atomicAdd(&h[((unsigned)dst[i]) >> CB_SHIFT], 1u);
    __syncthreads();
    for (int i = threadIdx.x; i < ncb; i += blockDim.x)
        if (h[i]) atomicAdd(&cntc[i], h[i]);
}

// single-block exclusive scan of cntc -> base, cursor
__global__ void k_scan(const unsigned int* __restrict__ cnt, int nb,
                       unsigned int* __restrict__ base,
                       unsigned int* __restrict__ cursor) {
    __shared__ unsigned int tsum[256];
    int t = threadIdx.x;
    int K = (nb + 255) / 256;
    unsigned int s = 0;
    for (int k = 0; k < K; k++) {
        int i = t * K + k;
        if (i < nb) s += cnt[i];
    }
    tsum[t] = s;
    __syncthreads();
    for (int off = 1; off < 256; off <<= 1) {
        unsigned int v = 0;
        if (t >= off) v = tsum[t - off];
        __syncthreads();
        if (t >= off) tsum[t] += v;
        __syncthreads();
    }
    unsigned int run = (t == 0) ? 0u : tsum[t - 1];
    for (int k = 0; k < K; k++) {
        int i = t * K + k;
        if (i < nb) { base[i] = run; cursor[i] = run; run += cnt[i]; }
    }
}

__global__ void k_fill_c(const int* __restrict__ src, const int* __restrict__ dst,
                         int e, int ncb, unsigned int* cursorc,
                         unsigned int* __restrict__ tmp) {
    __shared__ unsigned int h[NCB_MAX];
    __shared__ unsigned int lbase[NCB_MAX];
    for (int i = threadIdx.x; i < ncb; i += blockDim.x) h[i] = 0u;
    __syncthreads();
    int start = blockIdx.x * CHUNK;
    int end = min(start + CHUNK, e);
    for (int i = start + threadIdx.x; i < end; i += blockDim.x)
        atomicAdd(&h[((unsigned)dst[i]) >> CB_SHIFT], 1u);
    __syncthreads();
    for (int i = threadIdx.x; i < ncb; i += blockDim.x) {
        unsigned int c = h[i];
        lbase[i] = c ? atomicAdd(&cursorc[i], c) : 0u;
        h[i] = 0u;  // reuse as local rank cursor
    }
    __syncthreads();
    for (int i = start + threadIdx.x; i < end; i += blockDim.x) {
        unsigned int d = (unsigned)dst[i];
        unsigned int b = d >> CB_SHIFT;
        unsigned int r = atomicAdd(&h[b], 1u);
        tmp[lbase[b] + r] = (((unsigned)src[i]) << CB_SHIFT) | (d & (CB - 1u));
    }
}

// SPL blocks per bucket: LDS degree histogram slice -> coalesced global combine
__global__ __launch_bounds__(256) void
k_deg_split(const unsigned int* __restrict__ tmp,
            const unsigned int* __restrict__ basec,
            const unsigned int* __restrict__ cntc,
            unsigned int* __restrict__ deg, int n) {
    __shared__ unsigned int degl[CB];
    int t = threadIdx.x;
#pragma unroll
    for (int k = 0; k < CB / 256; k++) degl[t + 256 * k] = 0u;
    __syncthreads();
    int b = blockIdx.x / SPL, sl = blockIdx.x % SPL;
    unsigned int s = basec[b], m = cntc[b];
    for (unsigned int i = sl * 256u + t; i < m; i += SPL * 256u)
        atomicAdd(&degl[tmp[s + i] & (CB - 1u)], 1u);
    __syncthreads();
    int base = b * CB;
#pragma unroll
    for (int k = 0; k < CB / 256; k++) {
        int idx = t + 256 * k, node = base + idx;
        unsigned int c = degl[idx];
        if (node < n && c) atomicAdd(&deg[node], c);
    }
}

// inv = rsqrt(deg+1); xs4 = {x*inv, inv} pre-scale (removes inv gather from s1)
__global__ void k_inv(const unsigned int* __restrict__ deg,
                      const float* __restrict__ x,
                      float4* __restrict__ xs4, int n) {
    int i = blockIdx.x * blockDim.x + threadIdx.x;
    if (i >= n) return;
    float iv = rsqrtf((float)(deg[i] + 1u));   // +1 self-loop
    xs4[i] = make_float4(x[3 * i] * iv, x[3 * i + 1] * iv, x[3 * i + 2] * iv, iv);
}

// layer-1 aggregate: Σ inv[s]*x[s] per dst (inv[dst] factored to epilogue).
// per edge: 1 coalesced rec load + 1 float4 L2 gather + 3 LDS atomics.
__global__ __launch_bounds__(256) void
k_s1_split(const unsigned int* __restrict__ tmp,
           const unsigned int* __restrict__ basec,
           const unsigned int* __restrict__ cntc,
           const float4* __restrict__ xs4,
           float* __restrict__ agg0, float* __restrict__ agg1,
           float* __restrict__ agg2, int n) {
    __shared__ float a0[CB], a1[CB], a2[CB];   // 12 KB
    int t = threadIdx.x;
#pragma unroll
    for (int k = 0; k < CB / 256; k++) {
        a0[t + 256 * k] = 0.f; a1[t + 256 * k] = 0.f; a2[t + 256 * k] = 0.f;
    }
    __syncthreads();
    int b = blockIdx.x / SPL, sl = blockIdx.x % SPL;
    unsigned int s = basec[b], m = cntc[b];
    for (unsigned int i = sl * 256u + t; i < m; i += SPL * 256u) {
        unsigned int rec = tmp[s + i];
        unsigned int srcn = rec >> CB_SHIFT;
        unsigned int dl = rec & (CB - 1u);
        float4 v = xs4[srcn];                  // 1.6 MB table, L2-hit
        atomicAdd(&a0[dl], v.x);
        atomicAdd(&a1[dl], v.y);
        atomicAdd(&a2[dl], v.z);
    }
    __syncthreads();
    int base = b * CB;
#pragma unroll
    for (int k = 0; k < CB / 256; k++) {
        int idx = t + 256 * k, node = base + idx;
        if (node < n) {
            float p0 = a0[idx], p1 = a1[idx], p2 = a2[idx];
            if (p0 != 0.f) atomicAdd(&agg0[node], p0);   // coalesced combine
            if (p1 != 0.f) atomicAdd(&agg1[node], p1);
            if (p2 != 0.f) atomicAdd(&agg2[node], p2);
        }
    }
}

// epilogue: finish layer-1 (×inv[dst], self-loop, W1+b1+relu+W2),
// pre-scale t2s = inv*t2, init out = b2 + self-loop term
__global__ void k_epi(const float* __restrict__ agg0, const float* __restrict__ agg1,
                      const float* __restrict__ agg2, const float4* __restrict__ xs4,
                      const float* __restrict__ W1, const float* __restrict__ b1,
                      const float* __restrict__ W2, const float* __restrict__ b2,
                      float* __restrict__ t2s, float* __restrict__ out, int n) {
    int i = blockIdx.x * blockDim.x + threadIdx.x;
    if (i >= n) return;
    float4 xv = xs4[i];
    float iv = xv.w;
    float v0 = iv * (agg0[i] + xv.x);   // self-loop: + xs*iv = x*iv^2 = x/deg
    float v1 = iv * (agg1[i] + xv.y);
    float v2 = iv * (agg2[i] + xv.z);
    float acc = 0.f;
#pragma unroll
    for (int j = 0; j < HIDDEN; j++) {
        float h = fmaxf(fmaf(v0, W1[j], fmaf(v1, W1[HIDDEN + j],
                       fmaf(v2, W1[2 * HIDDEN + j], b1[j]))), 0.f);
        acc += h * W2[j];
    }
    t2s[i] = acc * iv;
    out[i] = b2[0] + acc * iv * iv;
}

// layer-2 aggregate: Σ t2s[src] per dst, ×inv[dst] at combine, += out
__global__ __launch_bounds__(256) void
k_s2_split(const unsigned int* __restrict__ tmp,
           const unsigned int* __restrict__ basec,
           const unsigned int* __restrict__ cntc,
           const float* __restrict__ t2s, const float4* __restrict__ xs4,
           float* __restrict__ out, int n) {
    __shared__ float o[CB];
    int t = threadIdx.x;
#pragma unroll
    for (int k = 0; k < CB / 256; k++) o[t + 256 * k] = 0.f;
    __syncthreads();
    int b = blockIdx.x / SPL, sl = blockIdx.x % SPL;
    unsigned int s = basec[b], m = cntc[b];
    for (unsigned int i = sl * 256u + t; i < m; i += SPL * 256u) {
        unsigned int rec = tmp[s + i];
        atomicAdd(&o[rec & (CB - 1u)], t2s[rec >> CB_SHIFT]);  // 400 KB, L2-hit
    }
    __syncthreads();
    int base = b * CB;
#pragma unroll
    for (int k = 0; k < CB / 256; k++) {
        int idx = t + 256 * k, node = base + idx;
        if (node < n) {
            float p = o[idx];
            if (p != 0.f) atomicAdd(&out[node], p * xs4[node].w);
        }
    }
}

// ======================= fallback (global-atomic) path =======================

__global__ void k_init_deg(unsigned int* deg, int n) {
    int i = blockIdx.x * blockDim.x + threadIdx.x;
    if (i < n) deg[i] = 1u;
}
__global__ void k_count_deg(const int* __restrict__ dst, unsigned int* deg, int e) {
    int i = blockIdx.x * blockDim.x + threadIdx.x;
    if (i < e) atomicAdd(&deg[dst[i]], 1u);
}
__global__ void k_invf(const unsigned int* __restrict__ deg, float* __restrict__ inv, int n) {
    int i = blockIdx.x * blockDim.x + threadIdx.x;
    if (i < n) inv[i] = rsqrtf((float)deg[i]);
}
__global__ void k_transform1(const float* __restrict__ x, const float* __restrict__ W1,
                             const float* __restrict__ b1, const float* __restrict__ inv,
                             float* __restrict__ t1, float* __restrict__ acc1, int n) {
    int tid = blockIdx.x * blockDim.x + threadIdx.x;
    if (tid >= n * HIDDEN) return;
    int i = tid >> 4, j = tid & 15;
    float t = x[3 * i] * W1[j] + x[3 * i + 1] * W1[HIDDEN + j] + x[3 * i + 2] * W1[2 * HIDDEN + j];
    t1[tid] = t;
    float iv = inv[i];
    acc1[tid] = b1[j] + t * iv * iv;
}
__global__ void k_scatter1(const int* __restrict__ src, const int* __restrict__ dst,
                           const float* __restrict__ inv, const float* __restrict__ t1,
                           float* acc1, int e) {
    long long tid = (long long)blockIdx.x * blockDim.x + threadIdx.x;
    if (tid >= (long long)e * HIDDEN) return;
    int eid = (int)(tid >> 4), j = (int)(tid & 15);
    int s = src[eid], d = dst[eid];
    atomicAdd(&acc1[d * HIDDEN + j], inv[s] * inv[d] * t1[s * HIDDEN + j]);
}
__global__ void k_transform2(const float* __restrict__ acc1, const float* __restrict__ W2,
                             const float* __restrict__ b2, const float* __restrict__ inv,
                             float* __restrict__ t2, float* __restrict__ out, int n) {
    int i = blockIdx.x * blockDim.x + threadIdx.x;
    if (i >= n) return;
    float t = 0.f;
#pragma unroll
    for (int j = 0; j < HIDDEN; j++) t += fmaxf(acc1[i * HIDDEN + j], 0.f) * W2[j];
    t2[i] = t;
    float iv = inv[i];
    out[i] = b2[0] + t * iv * iv;
}
__global__ void k_scatter2(const int* __restrict__ src, const int* __restrict__ dst,
                           const float* __restrict__ inv, const float* __restrict__ t2,
                           float* out, int e) {
    int i = blockIdx.x * blockDim.x + threadIdx.x;
    if (i >= e) return;
    int s = src[i], d = dst[i];
    atomicAdd(&out[d], inv[s] * inv[d] * t2[s]);
}

// ======================= launch =======================

extern "C" void kernel_launch(void* const* d_in, const int* in_sizes, int n_in,
                              void* d_out, int out_size, void* d_ws, size_t ws_size,
                              hipStream_t stream) {
    const float* x  = (const float*)d_in[0];
    const int*   ei = (const int*)d_in[1];
    const float* W1 = (const float*)d_in[2];
    const float* b1 = (const float*)d_in[3];
    const float* W2 = (const float*)d_in[4];
    const float* b2 = (const float*)d_in[5];
    float* out = (float*)d_out;

    int n = in_sizes[0] / 3;
    int e = in_sizes[1] / 2;
    const int* src = ei;
    const int* dst = ei + e;
    const int B = 256;

    int ncb = (n + CB - 1) / CB;
    // layout: xs4[n] | agg0[n] agg1[n] agg2[n] deg[n] | t2s[n] | cntc basec cursorc | tmp[e]
    size_t need = (size_t)n * 16 + (size_t)n * 16 + (size_t)n * 4
                + (size_t)ncb * 12 + (size_t)e * 4;
    bool use_split = (ncb <= NCB_MAX) && (n < (1 << 22)) && (ws_size >= need);

    if (use_split) {
        float4* xs4 = (float4*)d_ws;                          // n (16B-aligned base)
        float* agg0 = (float*)(xs4 + n);                      // n
        float* agg1 = agg0 + n;                               // n
        float* agg2 = agg1 + n;                               // n
        unsigned int* deg = (unsigned int*)(agg2 + n);        // n
        float* t2s = (float*)(deg + n);                       // n
        unsigned int* cntc    = (unsigned int*)(t2s + n);     // ncb
        unsigned int* basec   = cntc + ncb;                   // ncb
        unsigned int* cursorc = basec + ncb;                  // ncb
        unsigned int* tmp     = cursorc + ncb;                // e

        int gridE = (e + CHUNK - 1) / CHUNK;
        int gridN = (n + B - 1) / B;
        k_zero<<<(4 * n + ncb + B - 1) / B, B, 0, stream>>>(
            (unsigned int*)agg0, 4 * n, cntc, ncb);
        k_hist_c<<<gridE, B, 0, stream>>>(dst, e, ncb, cntc);
        k_scan<<<1, B, 0, stream>>>(cntc, ncb, basec, cursorc);
        k_fill_c<<<gridE, B, 0, stream>>>(src, dst, e, ncb, cursorc, tmp);
        k_deg_split<<<ncb * SPL, B, 0, stream>>>(tmp, basec, cntc, deg, n);
        k_inv<<<gridN, B, 0, stream>>>(deg, x, xs4, n);
        k_s1_split<<<ncb * SPL, B, 0, stream>>>(tmp, basec, cntc, xs4, agg0, agg1, agg2, n);
        k_epi<<<gridN, B, 0, stream>>>(agg0, agg1, agg2, xs4, W1, b1, W2, b2, t2s, out, n);
        k_s2_split<<<ncb * SPL, B, 0, stream>>>(tmp, basec, cntc, t2s, xs4, out, n);
    } else {
        unsigned int* deg = (unsigned int*)d_ws;
        float* inv  = (float*)(deg + n);
        float* t1   = inv + n;
        float* acc1 = t1 + (size_t)n * HIDDEN;
        float* t2   = acc1 + (size_t)n * HIDDEN;

        k_init_deg<<<(n + B - 1) / B, B, 0, stream>>>(deg, n);
        k_count_deg<<<(e + B - 1) / B, B, 0, stream>>>(dst, deg, e);
        k_invf<<<(n + B - 1) / B, B, 0, stream>>>(deg, inv, n);
        k_transform1<<<((long long)n * HIDDEN + B - 1) / B, B, 0, stream>>>(x, W1, b1, inv, t1, acc1, n);
        k_scatter1<<<((long long)e * HIDDEN + B - 1) / B, B, 0, stream>>>(src, dst, inv, t1, acc1, e);
        k_transform2<<<(n + B - 1) / B, B, 0, stream>>>(acc1, W2, b2, inv, t2, out, n);
        k_scatter2<<<(e + B - 1) / B, B, 0, stream>>>(src, dst, inv, t2, out, e);
    }
}

// Round 6
// 220.450 us; speedup vs baseline: 1.4795x; 1.0549x over previous
//
#include <hip/hip_runtime.h>

#define HIDDEN 16
#define CB 1024         // nodes per coarse bucket (power of two)
#define CB_SHIFT 10
#define NCB_MAX 512     // max coarse buckets
#define CHUNK 8192      // edges per block in hist/fill passes
#define SPL 8           // slice-blocks per bucket in accumulate kernels
#define ILP 8           // independent edges in flight per thread

// ======================= coarse-binned split path =======================

// zero agg0..agg2+deg (4n contiguous words) and cntc (ncb words)
__global__ void k_zero(unsigned int* aggdeg, int n4, unsigned int* cntc, int ncb) {
    int i = blockIdx.x * blockDim.x + threadIdx.x;
    if (i < n4) aggdeg[i] = 0u;
    else if (i < n4 + ncb) cntc[i - n4] = 0u;
}

__global__ void k_hist_c(const int* __restrict__ dst, int e, int ncb,
                         unsigned int* __restrict__ cntc) {
    __shared__ unsigned int h[NCB_MAX];
    for (int i = threadIdx.x; i < ncb; i += blockDim.x) h[i] = 0u;
    __syncthreads();
    int start = blockIdx.x * CHUNK;
    int end = min(start + CHUNK, e);
    int i = start + threadIdx.x;
    for (; i + 3 * 256 < end; i += 4 * 256) {   // ILP-4: 4 loads in flight
        unsigned d0 = dst[i], d1 = dst[i + 256], d2 = dst[i + 512], d3 = dst[i + 768];
        atomicAdd(&h[d0 >> CB_SHIFT], 1u);
        atomicAdd(&h[d1 >> CB_SHIFT], 1u);
        atomicAdd(&h[d2 >> CB_SHIFT], 1u);
        atomicAdd(&h[d3 >> CB_SHIFT], 1u);
    }
    for (; i < end; i += 256)
        atomicAdd(&h[((unsigned)dst[i]) >> CB_SHIFT], 1u);
    __syncthreads();
    for (int j = threadIdx.x; j < ncb; j += blockDim.x)
        if (h[j]) atomicAdd(&cntc[j], h[j]);
}

// single-block exclusive scan of cntc -> base, cursor
__global__ void k_scan(const unsigned int* __restrict__ cnt, int nb,
                       unsigned int* __restrict__ base,
                       unsigned int* __restrict__ cursor) {
    __shared__ unsigned int tsum[256];
    int t = threadIdx.x;
    int K = (nb + 255) / 256;
    unsigned int s = 0;
    for (int k = 0; k < K; k++) {
        int i = t * K + k;
        if (i < nb) s += cnt[i];
    }
    tsum[t] = s;
    __syncthreads();
    for (int off = 1; off < 256; off <<= 1) {
        unsigned int v = 0;
        if (t >= off) v = tsum[t - off];
        __syncthreads();
        if (t >= off) tsum[t] += v;
        __syncthreads();
    }
    unsigned int run = (t == 0) ? 0u : tsum[t - 1];
    for (int k = 0; k < K; k++) {
        int i = t * K + k;
        if (i < nb) { base[i] = run; cursor[i] = run; run += cnt[i]; }
    }
}

__global__ void k_fill_c(const int* __restrict__ src, const int* __restrict__ dst,
                         int e, int ncb, unsigned int* cursorc,
                         unsigned int* __restrict__ tmp) {
    __shared__ unsigned int h[NCB_MAX];
    __shared__ unsigned int lbase[NCB_MAX];
    for (int i = threadIdx.x; i < ncb; i += blockDim.x) h[i] = 0u;
    __syncthreads();
    int start = blockIdx.x * CHUNK;
    int end = min(start + CHUNK, e);
    int i = start + threadIdx.x;
    for (; i + 3 * 256 < end; i += 4 * 256) {
        unsigned d0 = dst[i], d1 = dst[i + 256], d2 = dst[i + 512], d3 = dst[i + 768];
        atomicAdd(&h[d0 >> CB_SHIFT], 1u);
        atomicAdd(&h[d1 >> CB_SHIFT], 1u);
        atomicAdd(&h[d2 >> CB_SHIFT], 1u);
        atomicAdd(&h[d3 >> CB_SHIFT], 1u);
    }
    for (; i < end; i += 256)
        atomicAdd(&h[((unsigned)dst[i]) >> CB_SHIFT], 1u);
    __syncthreads();
    for (int j = threadIdx.x; j < ncb; j += blockDim.x) {
        unsigned int c = h[j];
        lbase[j] = c ? atomicAdd(&cursorc[j], c) : 0u;
        h[j] = 0u;  // reuse as local rank cursor
    }
    __syncthreads();
    i = start + threadIdx.x;
    for (; i + 3 * 256 < end; i += 4 * 256) {   // ILP-4 on src/dst loads
        unsigned d0 = dst[i], d1 = dst[i + 256], d2 = dst[i + 512], d3 = dst[i + 768];
        unsigned s0 = src[i], s1 = src[i + 256], s2 = src[i + 512], s3 = src[i + 768];
        unsigned b0 = d0 >> CB_SHIFT, b1 = d1 >> CB_SHIFT;
        unsigned b2 = d2 >> CB_SHIFT, b3 = d3 >> CB_SHIFT;
        unsigned r0 = atomicAdd(&h[b0], 1u);
        unsigned r1 = atomicAdd(&h[b1], 1u);
        unsigned r2 = atomicAdd(&h[b2], 1u);
        unsigned r3 = atomicAdd(&h[b3], 1u);
        tmp[lbase[b0] + r0] = (s0 << CB_SHIFT) | (d0 & (CB - 1u));
        tmp[lbase[b1] + r1] = (s1 << CB_SHIFT) | (d1 & (CB - 1u));
        tmp[lbase[b2] + r2] = (s2 << CB_SHIFT) | (d2 & (CB - 1u));
        tmp[lbase[b3] + r3] = (s3 << CB_SHIFT) | (d3 & (CB - 1u));
    }
    for (; i < end; i += 256) {
        unsigned int d = (unsigned)dst[i];
        unsigned int b = d >> CB_SHIFT;
        unsigned int r = atomicAdd(&h[b], 1u);
        tmp[lbase[b] + r] = (((unsigned)src[i]) << CB_SHIFT) | (d & (CB - 1u));
    }
}

// SPL blocks per bucket: LDS degree histogram slice -> coalesced global combine
__global__ __launch_bounds__(256) void
k_deg_split(const unsigned int* __restrict__ tmp,
            const unsigned int* __restrict__ basec,
            const unsigned int* __restrict__ cntc,
            unsigned int* __restrict__ deg, int n) {
    __shared__ unsigned int degl[CB];
    int t = threadIdx.x;
#pragma unroll
    for (int k = 0; k < CB / 256; k++) degl[t + 256 * k] = 0u;
    __syncthreads();
    int b = blockIdx.x / SPL, sl = blockIdx.x % SPL;
    unsigned int s = basec[b], m = cntc[b];
    const unsigned STR = SPL * 256u;
    unsigned int i = sl * 256u + t;
    for (; i + (ILP - 1) * STR < m; i += ILP * STR) {
        unsigned r[ILP];
#pragma unroll
        for (int k = 0; k < ILP; k++) r[k] = tmp[s + i + k * STR];
#pragma unroll
        for (int k = 0; k < ILP; k++) atomicAdd(&degl[r[k] & (CB - 1u)], 1u);
    }
    for (; i < m; i += STR)
        atomicAdd(&degl[tmp[s + i] & (CB - 1u)], 1u);
    __syncthreads();
    int base = b * CB;
#pragma unroll
    for (int k = 0; k < CB / 256; k++) {
        int idx = t + 256 * k, node = base + idx;
        unsigned int c = degl[idx];
        if (node < n && c) atomicAdd(&deg[node], c);
    }
}

// inv = rsqrt(deg+1); xs4 = {x*inv, inv} pre-scale (removes inv gather from s1)
__global__ void k_inv(const unsigned int* __restrict__ deg,
                      const float* __restrict__ x,
                      float4* __restrict__ xs4, int n) {
    int i = blockIdx.x * blockDim.x + threadIdx.x;
    if (i >= n) return;
    float iv = rsqrtf((float)(deg[i] + 1u));   // +1 self-loop
    xs4[i] = make_float4(x[3 * i] * iv, x[3 * i + 1] * iv, x[3 * i + 2] * iv, iv);
}

// layer-1 aggregate: Σ inv[s]*x[s] per dst (inv[dst] factored to epilogue).
// ILP-8: 8 rec loads, then 8 float4 gathers, all in flight simultaneously.
__global__ __launch_bounds__(256) void
k_s1_split(const unsigned int* __restrict__ tmp,
           const unsigned int* __restrict__ basec,
           const unsigned int* __restrict__ cntc,
           const float4* __restrict__ xs4,
           float* __restrict__ agg0, float* __restrict__ agg1,
           float* __restrict__ agg2, int n) {
    __shared__ float a0[CB], a1[CB], a2[CB];   // 12 KB
    int t = threadIdx.x;
#pragma unroll
    for (int k = 0; k < CB / 256; k++) {
        a0[t + 256 * k] = 0.f; a1[t + 256 * k] = 0.f; a2[t + 256 * k] = 0.f;
    }
    __syncthreads();
    int b = blockIdx.x / SPL, sl = blockIdx.x % SPL;
    unsigned int s = basec[b], m = cntc[b];
    const unsigned STR = SPL * 256u;
    unsigned int i = sl * 256u + t;
    for (; i + (ILP - 1) * STR < m; i += ILP * STR) {
        unsigned r[ILP];
#pragma unroll
        for (int k = 0; k < ILP; k++) r[k] = tmp[s + i + k * STR];
        float4 v[ILP];
#pragma unroll
        for (int k = 0; k < ILP; k++) v[k] = xs4[r[k] >> CB_SHIFT];
#pragma unroll
        for (int k = 0; k < ILP; k++) {
            unsigned dl = r[k] & (CB - 1u);
            atomicAdd(&a0[dl], v[k].x);
            atomicAdd(&a1[dl], v[k].y);
            atomicAdd(&a2[dl], v[k].z);
        }
    }
    for (; i < m; i += STR) {
        unsigned rec = tmp[s + i];
        float4 v = xs4[rec >> CB_SHIFT];
        unsigned dl = rec & (CB - 1u);
        atomicAdd(&a0[dl], v.x);
        atomicAdd(&a1[dl], v.y);
        atomicAdd(&a2[dl], v.z);
    }
    __syncthreads();
    int base = b * CB;
#pragma unroll
    for (int k = 0; k < CB / 256; k++) {
        int idx = t + 256 * k, node = base + idx;
        if (node < n) {
            float p0 = a0[idx], p1 = a1[idx], p2 = a2[idx];
            if (p0 != 0.f) atomicAdd(&agg0[node], p0);   // coalesced combine
            if (p1 != 0.f) atomicAdd(&agg1[node], p1);
            if (p2 != 0.f) atomicAdd(&agg2[node], p2);
        }
    }
}

// epilogue: finish layer-1 (×inv[dst], self-loop, W1+b1+relu+W2),
// pre-scale t2s = inv*t2, init out = b2 + self-loop term
__global__ void k_epi(const float* __restrict__ agg0, const float* __restrict__ agg1,
                      const float* __restrict__ agg2, const float4* __restrict__ xs4,
                      const float* __restrict__ W1, const float* __restrict__ b1,
                      const float* __restrict__ W2, const float* __restrict__ b2,
                      float* __restrict__ t2s, float* __restrict__ out, int n) {
    int i = blockIdx.x * blockDim.x + threadIdx.x;
    if (i >= n) return;
    float4 xv = xs4[i];
    float iv = xv.w;
    float v0 = iv * (agg0[i] + xv.x);   // self-loop: + xs*iv = x*iv^2 = x/deg
    float v1 = iv * (agg1[i] + xv.y);
    float v2 = iv * (agg2[i] + xv.z);
    float acc = 0.f;
#pragma unroll
    for (int j = 0; j < HIDDEN; j++) {
        float h = fmaxf(fmaf(v0, W1[j], fmaf(v1, W1[HIDDEN + j],
                       fmaf(v2, W1[2 * HIDDEN + j], b1[j]))), 0.f);
        acc += h * W2[j];
    }
    t2s[i] = acc * iv;
    out[i] = b2[0] + acc * iv * iv;
}

// layer-2 aggregate: Σ t2s[src] per dst, ×inv[dst] at combine, += out
__global__ __launch_bounds__(256) void
k_s2_split(const unsigned int* __restrict__ tmp,
           const unsigned int* __restrict__ basec,
           const unsigned int* __restrict__ cntc,
           const float* __restrict__ t2s, const float4* __restrict__ xs4,
           float* __restrict__ out, int n) {
    __shared__ float o[CB];
    int t = threadIdx.x;
#pragma unroll
    for (int k = 0; k < CB / 256; k++) o[t + 256 * k] = 0.f;
    __syncthreads();
    int b = blockIdx.x / SPL, sl = blockIdx.x % SPL;
    unsigned int s = basec[b], m = cntc[b];
    const unsigned STR = SPL * 256u;
    unsigned int i = sl * 256u + t;
    for (; i + (ILP - 1) * STR < m; i += ILP * STR) {
        unsigned r[ILP];
#pragma unroll
        for (int k = 0; k < ILP; k++) r[k] = tmp[s + i + k * STR];
        float v[ILP];
#pragma unroll
        for (int k = 0; k < ILP; k++) v[k] = t2s[r[k] >> CB_SHIFT];
#pragma unroll
        for (int k = 0; k < ILP; k++) atomicAdd(&o[r[k] & (CB - 1u)], v[k]);
    }
    for (; i < m; i += STR) {
        unsigned rec = tmp[s + i];
        atomicAdd(&o[rec & (CB - 1u)], t2s[rec >> CB_SHIFT]);
    }
    __syncthreads();
    int base = b * CB;
#pragma unroll
    for (int k = 0; k < CB / 256; k++) {
        int idx = t + 256 * k, node = base + idx;
        if (node < n) {
            float p = o[idx];
            if (p != 0.f) atomicAdd(&out[node], p * xs4[node].w);
        }
    }
}

// ======================= fallback (global-atomic) path =======================

__global__ void k_init_deg(unsigned int* deg, int n) {
    int i = blockIdx.x * blockDim.x + threadIdx.x;
    if (i < n) deg[i] = 1u;
}
__global__ void k_count_deg(const int* __restrict__ dst, unsigned int* deg, int e) {
    int i = blockIdx.x * blockDim.x + threadIdx.x;
    if (i < e) atomicAdd(&deg[dst[i]], 1u);
}
__global__ void k_invf(const unsigned int* __restrict__ deg, float* __restrict__ inv, int n) {
    int i = blockIdx.x * blockDim.x + threadIdx.x;
    if (i < n) inv[i] = rsqrtf((float)deg[i]);
}
__global__ void k_transform1(const float* __restrict__ x, const float* __restrict__ W1,
                             const float* __restrict__ b1, const float* __restrict__ inv,
                             float* __restrict__ t1, float* __restrict__ acc1, int n) {
    int tid = blockIdx.x * blockDim.x + threadIdx.x;
    if (tid >= n * HIDDEN) return;
    int i = tid >> 4, j = tid & 15;
    float t = x[3 * i] * W1[j] + x[3 * i + 1] * W1[HIDDEN + j] + x[3 * i + 2] * W1[2 * HIDDEN + j];
    t1[tid] = t;
    float iv = inv[i];
    acc1[tid] = b1[j] + t * iv * iv;
}
__global__ void k_scatter1(const int* __restrict__ src, const int* __restrict__ dst,
                           const float* __restrict__ inv, const float* __restrict__ t1,
                           float* acc1, int e) {
    long long tid = (long long)blockIdx.x * blockDim.x + threadIdx.x;
    if (tid >= (long long)e * HIDDEN) return;
    int eid = (int)(tid >> 4), j = (int)(tid & 15);
    int s = src[eid], d = dst[eid];
    atomicAdd(&acc1[d * HIDDEN + j], inv[s] * inv[d] * t1[s * HIDDEN + j]);
}
__global__ void k_transform2(const float* __restrict__ acc1, const float* __restrict__ W2,
                             const float* __restrict__ b2, const float* __restrict__ inv,
                             float* __restrict__ t2, float* __restrict__ out, int n) {
    int i = blockIdx.x * blockDim.x + threadIdx.x;
    if (i >= n) return;
    float t = 0.f;
#pragma unroll
    for (int j = 0; j < HIDDEN; j++) t += fmaxf(acc1[i * HIDDEN + j], 0.f) * W2[j];
    t2[i] = t;
    float iv = inv[i];
    out[i] = b2[0] + t * iv * iv;
}
__global__ void k_scatter2(const int* __restrict__ src, const int* __restrict__ dst,
                           const float* __restrict__ inv, const float* __restrict__ t2,
                           float* out, int e) {
    int i = blockIdx.x * blockDim.x + threadIdx.x;
    if (i >= e) return;
    int s = src[i], d = dst[i];
    atomicAdd(&out[d], inv[s] * inv[d] * t2[s]);
}

// ======================= launch =======================

extern "C" void kernel_launch(void* const* d_in, const int* in_sizes, int n_in,
                              void* d_out, int out_size, void* d_ws, size_t ws_size,
                              hipStream_t stream) {
    const float* x  = (const float*)d_in[0];
    const int*   ei = (const int*)d_in[1];
    const float* W1 = (const float*)d_in[2];
    const float* b1 = (const float*)d_in[3];
    const float* W2 = (const float*)d_in[4];
    const float* b2 = (const float*)d_in[5];
    float* out = (float*)d_out;

    int n = in_sizes[0] / 3;
    int e = in_sizes[1] / 2;
    const int* src = ei;
    const int* dst = ei + e;
    const int B = 256;

    int ncb = (n + CB - 1) / CB;
    size_t need = (size_t)n * 16 + (size_t)n * 16 + (size_t)n * 4
                + (size_t)ncb * 12 + (size_t)e * 4;
    bool use_split = (ncb <= NCB_MAX) && (n < (1 << 22)) && (ws_size >= need);

    if (use_split) {
        float4* xs4 = (float4*)d_ws;                          // n (16B-aligned base)
        float* agg0 = (float*)(xs4 + n);                      // n
        float* agg1 = agg0 + n;                               // n
        float* agg2 = agg1 + n;                               // n
        unsigned int* deg = (unsigned int*)(agg2 + n);        // n
        float* t2s = (float*)(deg + n);                       // n
        unsigned int* cntc    = (unsigned int*)(t2s + n);     // ncb
        unsigned int* basec   = cntc + ncb;                   // ncb
        unsigned int* cursorc = basec + ncb;                  // ncb
        unsigned int* tmp     = cursorc + ncb;                // e

        int gridE = (e + CHUNK - 1) / CHUNK;
        int gridN = (n + B - 1) / B;
        k_zero<<<(4 * n + ncb + B - 1) / B, B, 0, stream>>>(
            (unsigned int*)agg0, 4 * n, cntc, ncb);
        k_hist_c<<<gridE, B, 0, stream>>>(dst, e, ncb, cntc);
        k_scan<<<1, B, 0, stream>>>(cntc, ncb, basec, cursorc);
        k_fill_c<<<gridE, B, 0, stream>>>(src, dst, e, ncb, cursorc, tmp);
        k_deg_split<<<ncb * SPL, B, 0, stream>>>(tmp, basec, cntc, deg, n);
        k_inv<<<gridN, B, 0, stream>>>(deg, x, xs4, n);
        k_s1_split<<<ncb * SPL, B, 0, stream>>>(tmp, basec, cntc, xs4, agg0, agg1, agg2, n);
        k_epi<<<gridN, B, 0, stream>>>(agg0, agg1, agg2, xs4, W1, b1, W2, b2, t2s, out, n);
        k_s2_split<<<ncb * SPL, B, 0, stream>>>(tmp, basec, cntc, t2s, xs4, out, n);
    } else {
        unsigned int* deg = (unsigned int*)d_ws;
        float* inv  = (float*)(deg + n);
        float* t1   = inv + n;
        float* acc1 = t1 + (size_t)n * HIDDEN;
        float* t2   = acc1 + (size_t)n * HIDDEN;

        k_init_deg<<<(n + B - 1) / B, B, 0, stream>>>(deg, n);
        k_count_deg<<<(e + B - 1) / B, B, 0, stream>>>(dst, deg, e);
        k_invf<<<(n + B - 1) / B, B, 0, stream>>>(deg, inv, n);
        k_transform1<<<((long long)n * HIDDEN + B - 1) / B, B, 0, stream>>>(x, W1, b1, inv, t1, acc1, n);
        k_scatter1<<<((long long)e * HIDDEN + B - 1) / B, B, 0, stream>>>(src, dst, inv, t1, acc1, e);
        k_transform2<<<(n + B - 1) / B, B, 0, stream>>>(acc1, W2, b2, inv, t2, out, n);
        k_scatter2<<<(e + B - 1) / B, B, 0, stream>>>(src, dst, inv, t2, out, e);
    }
}